// Round 10
// baseline (98.472 us; speedup 1.0000x reference)
//
#include <hip/hip_runtime.h>
#include <hip/hip_bf16.h>

#define T_TOK 2048
#define H_DIM 1024
#define I_DIM 768
#define NEXP  8
#define WPE   6291456   // weight elems per array (E*I*H)

typedef short bf16x8  __attribute__((ext_vector_type(8)));
typedef short short4v __attribute__((ext_vector_type(4)));
typedef float f32x4   __attribute__((ext_vector_type(4)));

__device__ __forceinline__ short f2bf(float f) {
  __bf16 b = (__bf16)f;
  return __builtin_bit_cast(short, b);
}
__device__ __forceinline__ void gload16(const void* g, void* l) {
  __builtin_amdgcn_global_load_lds(
      (const __attribute__((address_space(1))) void*)g,
      (__attribute__((address_space(3))) void*)l, 16, 0, 0);
}
__device__ __forceinline__ int padcnt(int c) { return (c + 63) & ~63; }
__device__ __forceinline__ int ebase(const int* __restrict__ cnts, int e) {
  int b = 0;
#pragma unroll
  for (int i = 0; i < NEXP; ++i)
    if (i < e) b += padcnt(cnts[i]);
  return b;
}
// full 3-term XOR swizzle (T2): rows {r, r+4} differ, rows {r, r+8} 2-way (free, m136)
__device__ __forceinline__ int swz(int row, int g) {
  return g ^ (row & 3) ^ ((row >> 2) & 1);
}

// ws layout: 0: counts[8] | 256: lists[8*2048 ints] | 131072: wbf (gate++up++down bf16)
// 37879808: xc | 48365568: h

// ---- kernel A: routing compaction (8 blocks x 512)
__global__ __launch_bounds__(512) void compact_k(const float* __restrict__ routw,
                                                 int* __restrict__ wsI) {
  __shared__ int sc[8];
  int e = blockIdx.x, lane = threadIdx.x & 63, w = threadIdx.x >> 6;
  unsigned long long mk[4];
  int cnt = 0;
#pragma unroll
  for (int c = 0; c < 4; ++c) {
    int tk = w * 256 + c * 64 + lane;
    float v = routw[(size_t)tk * NEXP + e];
    mk[c] = __ballot(v > 0.f);
    cnt += __popcll(mk[c]);
  }
  if (lane == 0) sc[w] = cnt;
  __syncthreads();
  int run = 0;
#pragma unroll
  for (int j = 0; j < 8; ++j)
    if (j < w) run += sc[j];
#pragma unroll
  for (int c = 0; c < 4; ++c) {
    int tk = w * 256 + c * 64 + lane;
    if ((mk[c] >> lane) & 1ull) {
      int pos = __popcll(mk[c] & ((1ull << lane) - 1));
      wsI[64 + e * T_TOK + run + pos] = tk;
    }
    run += __popcll(mk[c]);
  }
  if (w == 7 && lane == 0) wsI[e] = run;
}

// ---- kernel B: xgather (blocks 0..4095) + gate/up conv (4096..7167), 256 thr
__global__ __launch_bounds__(256) void gatherconv_k(const float* __restrict__ x,
                                                    const float* __restrict__ gw,
                                                    const float* __restrict__ uw,
                                                    const int* __restrict__ wsI,
                                                    unsigned short* __restrict__ xc,
                                                    unsigned short* __restrict__ wbf) {
  int bid = blockIdx.x;
  if (bid < 4096) {            // xgather: 4 rows/block
    int e = bid >> 9, rb = bid & 511;
    int cnt = wsI[e];
    int pad = padcnt(cnt);
    int r = rb * 4 + (threadIdx.x >> 6);
    if (r >= pad) return;
    int base = ebase(wsI, e);
    int col = (threadIdx.x & 63) * 16;
    unsigned short* dst = xc + (size_t)(base + r) * H_DIM + col;
    if (r < cnt) {
      int tok = wsI[64 + e * T_TOK + r];
      const float* sr = x + (size_t)tok * H_DIM + col;
#pragma unroll
      for (int j = 0; j < 4; ++j) {
        float4 v = *(const float4*)(sr + j * 4);
        short4v b = {f2bf(v.x), f2bf(v.y), f2bf(v.z), f2bf(v.w)};
        *(short4v*)(dst + j * 4) = b;
      }
    } else {
#pragma unroll
      for (int j = 0; j < 4; ++j) {
        short4v z = {0, 0, 0, 0};
        *(short4v*)(dst + j * 4) = z;
      }
    }
  } else {                     // gate+up fp32->bf16
    size_t off = ((size_t)(bid - 4096) * 256 + threadIdx.x) * 16;
    int a = (off >= (size_t)WPE) ? 1 : 0;
    size_t rem = off - (size_t)a * WPE;
    const float* s = (a ? uw : gw) + rem;
    unsigned short* o = wbf + (size_t)a * WPE + rem;
#pragma unroll
    for (int j = 0; j < 4; ++j) {
      float4 v = *(const float4*)(s + j * 4);
      short4v b = {f2bf(v.x), f2bf(v.y), f2bf(v.z), f2bf(v.w)};
      *(short4v*)(o + j * 4) = b;
    }
  }
}

// ---- kernel C: gemm1 (slots 0..3071) + down-conv (3072..6143) + zerofill (6144..7167)
// gemm1: h = silu(Xc Wg^T)*(Xc Wu^T). Tile M64 x (G64++U64), BK=32, 128 thr / 2 waves,
// wave tile 64x64 (32 FLOP per LDS byte). LDS 2 x 12KB = 24KB -> 6 blk/CU.
// Simple m97 2-phase loop; overlap comes from co-resident blocks (m114).
__global__ __launch_bounds__(128, 3) void gemm1_k(
    const unsigned short* __restrict__ xc, unsigned short* __restrict__ wbf,
    const int* __restrict__ wsI, unsigned short* __restrict__ h,
    const float* __restrict__ dw, float* __restrict__ out) {
  int bid = blockIdx.x;
  int tid = threadIdx.x;
  if (bid >= 3072) {
    if (bid < 6144) {          // down fp32->bf16 (consumer: gemm2)
      size_t off = ((size_t)(bid - 3072) * 128 + tid) * 16;
      const float* s = dw + off;
      unsigned short* o = wbf + 2 * (size_t)WPE + off;
#pragma unroll
      for (int j = 0; j < 4; ++j) {
        float4 v = *(const float4*)(s + j * 4);
        short4v b = {f2bf(v.x), f2bf(v.y), f2bf(v.z), f2bf(v.w)};
        *(short4v*)(o + j * 4) = b;
      }
    } else {                   // zerofill out (consumer: gemm2)
      size_t off = ((size_t)(bid - 6144) * 128 + tid) * 16;
      f32x4 z = {0.f, 0.f, 0.f, 0.f};
#pragma unroll
      for (int j = 0; j < 4; ++j) *(f32x4*)(out + off + j * 4) = z;
    }
    return;
  }
  int e = bid & 7, rr = bid >> 3;
  int mt = rr & 31, nt = rr >> 5;       // mt 0..31, nt 0..11
  int cnt = wsI[e];
  int m0 = mt * 64;
  if (m0 >= cnt) return;
  int base = ebase(wsI, e);
  int g0 = nt * 64;                     // 64 G-cols (and same 64 U-cols)

  __shared__ unsigned short ls[2][6144];  // A[64][32] @0 (2048 sh), B[128][32] @2048 (4096 sh)

  int lane = tid & 63, w = tid >> 6;    // w 0..1
  int fr = lane & 15, fg = lane >> 4;
  int srow = lane >> 2;
  int scol = swz(srow, lane & 3) * 8;   // pre-swizzled source col (shorts)

  const unsigned short* gate_bf = wbf;
  const unsigned short* up_bf   = wbf + WPE;

  // staging: A chunks {w, w+2} (16 rows each); B chunks {w, w+2, w+4, w+6} of 8
  const unsigned short* srcA[2];
  const unsigned short* srcB[4];
  int ldA[2], ldB[4];
#pragma unroll
  for (int i = 0; i < 2; ++i) {
    int c = w + 2 * i;
    ldA[i] = c * 512;
    srcA[i] = xc + (size_t)(base + m0 + 16 * c + srow) * H_DIM + scol;
  }
#pragma unroll
  for (int i = 0; i < 4; ++i) {
    int c = w + 2 * i;
    ldB[i] = 2048 + c * 512;
    srcB[i] = ((c < 4) ? gate_bf + (size_t)(e * I_DIM + g0 + 16 * c + srow) * H_DIM
                       : up_bf   + (size_t)(e * I_DIM + g0 + 16 * (c - 4) + srow) * H_DIM) + scol;
  }

  // read offsets (shorts): A rows m*16+fr; B rows: n<2 -> G wn*32+n*16+fr, n>=2 -> U +64
  int roA[4], roB[4];
#pragma unroll
  for (int m = 0; m < 4; ++m) {
    int r2 = m * 16 + fr;
    roA[m] = r2 * 32 + (swz(r2, fg) << 3);
  }
#pragma unroll
  for (int n = 0; n < 4; ++n) {
    int r2 = (n < 2) ? (w * 32 + n * 16 + fr) : (64 + w * 32 + (n - 2) * 16 + fr);
    roB[n] = 2048 + r2 * 32 + (swz(r2, fg) << 3);
  }

  f32x4 acc[4][4] = {};   // [m][n]: n 0,1 = G; 2,3 = U

#define STG1(buf, k)                                        \
  do {                                                      \
    _Pragma("unroll") for (int i = 0; i < 2; ++i)           \
      gload16(srcA[i] + (k) * 32, &ls[buf][ldA[i]]);        \
    _Pragma("unroll") for (int i = 0; i < 4; ++i)           \
      gload16(srcB[i] + (k) * 32, &ls[buf][ldB[i]]);        \
  } while (0)

  STG1(0, 0);
  __syncthreads();
  for (int k = 0; k < 32; ++k) {
    int cur = k & 1;
    if (k + 1 < 32) STG1(cur ^ 1, k + 1);
    bf16x8 af[4], bv[4];
#pragma unroll
    for (int m = 0; m < 4; ++m) af[m] = *(const bf16x8*)&ls[cur][roA[m]];
#pragma unroll
    for (int n = 0; n < 4; ++n) bv[n] = *(const bf16x8*)&ls[cur][roB[n]];
#pragma unroll
    for (int m = 0; m < 4; ++m)
#pragma unroll
      for (int n = 0; n < 4; ++n)
        acc[m][n] = __builtin_amdgcn_mfma_f32_16x16x32_bf16(af[m], bv[n], acc[m][n], 0, 0, 0);
    __syncthreads();
  }
#undef STG1

#pragma unroll
  for (int m = 0; m < 4; ++m)
#pragma unroll
    for (int j = 0; j < 4; ++j) {
      int row = m * 16 + fg * 4 + j;   // C/D: col=lane&15, row=(lane>>4)*4+reg
      size_t rb2 = (size_t)(base + m0 + row) * I_DIM + g0;
#pragma unroll
      for (int jn = 0; jn < 2; ++jn) {
        float g = acc[m][jn][j];
        float u = acc[m][jn + 2][j];
        h[rb2 + w * 32 + jn * 16 + fr] = (unsigned short)f2bf(g * u / (1.f + __expf(-g)));
      }
    }
}

// ---- kernel D: gemm2: out[t] += rw * (h_e down^T). Tile M64 x N128, BK=32,
// 128 thr / 2 waves, wave tile 64x64, same structure. grid 8*32*8 = 2048.
__global__ __launch_bounds__(128, 3) void gemm2_k(
    const unsigned short* __restrict__ h, const unsigned short* __restrict__ wbf,
    const int* __restrict__ wsI, const float* __restrict__ routw,
    float* __restrict__ out) {
  int e = blockIdx.x & 7, rr = blockIdx.x >> 3;
  int mt = rr & 31, nt = rr >> 5;       // nt 0..7
  int cnt = wsI[e];
  int m0 = mt * 64;
  if (m0 >= cnt) return;
  int base = ebase(wsI, e);
  int n0 = nt * 128;
  const unsigned short* down_bf = wbf + 2 * (size_t)WPE;

  __shared__ unsigned short ls[2][6144];  // A[64][32] @0, B[128][32] @2048

  int tid = threadIdx.x, lane = tid & 63, w = tid >> 6;
  int fr = lane & 15, fg = lane >> 4;
  int srow = lane >> 2;
  int scol = swz(srow, lane & 3) * 8;

  const unsigned short* srcA[2];
  const unsigned short* srcB[4];
  int ldA[2], ldB[4];
#pragma unroll
  for (int i = 0; i < 2; ++i) {
    int c = w + 2 * i;
    ldA[i] = c * 512;
    srcA[i] = h + (size_t)(base + m0 + 16 * c + srow) * I_DIM + scol;
  }
#pragma unroll
  for (int i = 0; i < 4; ++i) {
    int c = w + 2 * i;
    ldB[i] = 2048 + c * 512;
    srcB[i] = down_bf + (size_t)(e * H_DIM + n0 + 16 * c + srow) * I_DIM + scol;
  }

  int roA[4], roB[4];
#pragma unroll
  for (int m = 0; m < 4; ++m) {
    int r2 = m * 16 + fr;
    roA[m] = r2 * 32 + (swz(r2, fg) << 3);
  }
#pragma unroll
  for (int n = 0; n < 4; ++n) {
    int r2 = w * 64 + n * 16 + fr;
    roB[n] = 2048 + r2 * 32 + (swz(r2, fg) << 3);
  }

  f32x4 acc[4][4] = {};

#define STG2(buf, k)                                        \
  do {                                                      \
    _Pragma("unroll") for (int i = 0; i < 2; ++i)           \
      gload16(srcA[i] + (k) * 32, &ls[buf][ldA[i]]);        \
    _Pragma("unroll") for (int i = 0; i < 4; ++i)           \
      gload16(srcB[i] + (k) * 32, &ls[buf][ldB[i]]);        \
  } while (0)

  STG2(0, 0);
  __syncthreads();
  for (int k = 0; k < 24; ++k) {
    int cur = k & 1;
    if (k + 1 < 24) STG2(cur ^ 1, k + 1);
    bf16x8 af[4], bv[4];
#pragma unroll
    for (int m = 0; m < 4; ++m) af[m] = *(const bf16x8*)&ls[cur][roA[m]];
#pragma unroll
    for (int n = 0; n < 4; ++n) bv[n] = *(const bf16x8*)&ls[cur][roB[n]];
#pragma unroll
    for (int m = 0; m < 4; ++m)
#pragma unroll
      for (int n = 0; n < 4; ++n)
        acc[m][n] = __builtin_amdgcn_mfma_f32_16x16x32_bf16(af[m], bv[n], acc[m][n], 0, 0, 0);
    __syncthreads();
  }
#undef STG2

#pragma unroll
  for (int m = 0; m < 4; ++m)
#pragma unroll
    for (int j = 0; j < 4; ++j) {
      int row = m * 16 + fg * 4 + j;
      int grow = m0 + row;
      if (grow < cnt) {
        int tk = wsI[64 + e * T_TOK + grow];
        float rw = routw[(size_t)tk * NEXP + e];
        float* orow = out + (size_t)tk * H_DIM + n0 + w * 64;
#pragma unroll
        for (int n = 0; n < 4; ++n)
          atomicAdd(orow + n * 16 + fr, acc[m][n][j] * rw);
      }
    }
}

extern "C" void kernel_launch(void* const* d_in, const int* in_sizes, int n_in,
                              void* d_out, int out_size, void* d_ws, size_t ws_size,
                              hipStream_t stream) {
  const float* x      = (const float*)d_in[0];
  const float* gate_w = (const float*)d_in[1];
  const float* up_w   = (const float*)d_in[2];
  const float* down_w = (const float*)d_in[3];
  const float* routw  = (const float*)d_in[4];
  float* out = (float*)d_out;
  int* wsI = (int*)d_ws;

  unsigned short* wbf = (unsigned short*)((char*)d_ws + 131072);
  unsigned short* xc  = (unsigned short*)((char*)d_ws + 37879808);
  unsigned short* h   = (unsigned short*)((char*)d_ws + 48365568);

  compact_k<<<8, 512, 0, stream>>>(routw, wsI);
  gatherconv_k<<<7168, 256, 0, stream>>>(x, gate_w, up_w, wsI, xc, wbf);
  gemm1_k<<<7168, 128, 0, stream>>>(xc, wbf, wsI, h, down_w, out);
  gemm2_k<<<2048, 128, 0, stream>>>(h, wbf, wsI, routw, out);
}

// Round 11
// 93.518 us; speedup vs baseline: 1.0530x; 1.0530x over previous
//
#include <hip/hip_runtime.h>
#include <hip/hip_bf16.h>

#define T_TOK 2048
#define H_DIM 1024
#define I_DIM 768
#define NEXP  8
#define WPE   6291456   // weight elems per array (E*I*H)

typedef short bf16x8  __attribute__((ext_vector_type(8)));
typedef short short4v __attribute__((ext_vector_type(4)));
typedef float f32x4   __attribute__((ext_vector_type(4)));

__device__ __forceinline__ short f2bf(float f) {
  __bf16 b = (__bf16)f;
  return __builtin_bit_cast(short, b);
}
__device__ __forceinline__ void gload16(const void* g, void* l) {
  __builtin_amdgcn_global_load_lds(
      (const __attribute__((address_space(1))) void*)g,
      (__attribute__((address_space(3))) void*)l, 16, 0, 0);
}
__device__ __forceinline__ int padcnt(int c) { return (c + 127) & ~127; }  // =M-tile: no cross-expert writes
__device__ __forceinline__ int ebase(const int* __restrict__ cnts, int e) {
  int b = 0;
#pragma unroll
  for (int i = 0; i < NEXP; ++i)
    if (i < e) b += padcnt(cnts[i]);
  return b;
}

// ws layout: 0: counts[8] | 256: lists[8*2048 ints] | 131072: wbf (gate++up++down bf16)
// 37879808: xc (5120*1024 bf16) | 48365568: h (5120*768 bf16)

// ---- kernel A: routing compaction (8 blocks x 512)
__global__ __launch_bounds__(512) void compact_k(const float* __restrict__ routw,
                                                 int* __restrict__ wsI) {
  __shared__ int sc[8];
  int e = blockIdx.x, lane = threadIdx.x & 63, w = threadIdx.x >> 6;
  unsigned long long mk[4];
  int cnt = 0;
#pragma unroll
  for (int c = 0; c < 4; ++c) {
    int tk = w * 256 + c * 64 + lane;
    float v = routw[(size_t)tk * NEXP + e];
    mk[c] = __ballot(v > 0.f);
    cnt += __popcll(mk[c]);
  }
  if (lane == 0) sc[w] = cnt;
  __syncthreads();
  int run = 0;
#pragma unroll
  for (int j = 0; j < 8; ++j)
    if (j < w) run += sc[j];
#pragma unroll
  for (int c = 0; c < 4; ++c) {
    int tk = w * 256 + c * 64 + lane;
    if ((mk[c] >> lane) & 1ull) {
      int pos = __popcll(mk[c] & ((1ull << lane) - 1));
      wsI[64 + e * T_TOK + run + pos] = tk;
    }
    run += __popcll(mk[c]);
  }
  if (w == 7 && lane == 0) wsI[e] = run;
}

// ---- kernel B: ALL bandwidth work, no GEMM contention.
// blocks [0,4096): xgather | [4096,8704): wconv g/u/d | [8704,9216): zerofill out
__global__ __launch_bounds__(256) void pre_k(const float* __restrict__ x,
                                             const float* __restrict__ gw,
                                             const float* __restrict__ uw,
                                             const float* __restrict__ dw,
                                             const int* __restrict__ wsI,
                                             unsigned short* __restrict__ xc,
                                             unsigned short* __restrict__ wbf,
                                             float* __restrict__ out) {
  int bid = blockIdx.x, tid = threadIdx.x;
  if (bid < 4096) {            // xgather: 4 rows/block, zero-pad to pad128
    int e = bid >> 9, rb = bid & 511;
    int cnt = wsI[e];
    int pad = padcnt(cnt);
    int r = rb * 4 + (tid >> 6);
    if (r >= pad) return;
    int base = ebase(wsI, e);
    int col = (tid & 63) * 16;
    unsigned short* dst = xc + (size_t)(base + r) * H_DIM + col;
    if (r < cnt) {
      int tok = wsI[64 + e * T_TOK + r];
      const float* sr = x + (size_t)tok * H_DIM + col;
#pragma unroll
      for (int j = 0; j < 4; ++j) {
        float4 v = *(const float4*)(sr + j * 4);
        short4v b = {f2bf(v.x), f2bf(v.y), f2bf(v.z), f2bf(v.w)};
        *(short4v*)(dst + j * 4) = b;
      }
    } else {
#pragma unroll
      for (int j = 0; j < 4; ++j) {
        short4v z = {0, 0, 0, 0};
        *(short4v*)(dst + j * 4) = z;
      }
    }
  } else if (bid < 8704) {     // wconv: gate ++ up ++ down fp32->bf16, exact cover
    size_t off = ((size_t)(bid - 4096) * 256 + tid) * 16;
    int a = (int)(off / (size_t)WPE);
    size_t rem = off - (size_t)a * WPE;
    const float* s = ((a == 0) ? gw : (a == 1) ? uw : dw) + rem;
    unsigned short* o = wbf + (size_t)a * WPE + rem;
#pragma unroll
    for (int j = 0; j < 4; ++j) {
      float4 v = *(const float4*)(s + j * 4);
      short4v b = {f2bf(v.x), f2bf(v.y), f2bf(v.z), f2bf(v.w)};
      *(short4v*)(o + j * 4) = b;
    }
  } else {                     // zerofill out: 512 blocks x 256 thr x 16 floats
    size_t off = ((size_t)(bid - 8704) * 256 + tid) * 16;
    f32x4 z = {0.f, 0.f, 0.f, 0.f};
#pragma unroll
    for (int j = 0; j < 4; ++j) *(f32x4*)(out + off + j * 4) = z;
  }
}

// ---- shared pipeline macro: counted-vmcnt barrier (depth-5 ring, 3 loads/half/wave)
#define WB(v)                                              \
  do {                                                     \
    asm volatile("s_waitcnt vmcnt(" #v ")" ::: "memory");  \
    __builtin_amdgcn_s_barrier();                          \
    __builtin_amdgcn_sched_barrier(0);                     \
  } while (0)

// ---- kernel C: gemm1: h = silu(Xc Wg^T)*(Xc Wu^T).
// Tile M128 x (G128++U128), BK=32 halves, 8 waves (2Mx4N), wave tile 64x64.
// Depth-5 half-ring (120KB LDS, 1 blk/CU), stage 4 ahead, vmcnt(6): 2 halves always in flight.
// grid = 8e * 16mt * 6nt = 768 (e=bid&7 -> XCD pin). NO graft blocks.
__global__ __launch_bounds__(512, 2) void gemm1_k(
    const unsigned short* __restrict__ xc, const unsigned short* __restrict__ wbf,
    const int* __restrict__ wsI, unsigned short* __restrict__ h) {
  int e = blockIdx.x & 7, rr = blockIdx.x >> 3;
  int mt = rr & 15, nt = rr >> 4;       // nt 0..5
  int cnt = wsI[e];
  int m0 = mt * 128;
  if (m0 >= cnt) return;
  int base = ebase(wsI, e);
  int n0 = nt * 128;

  __shared__ unsigned short ls[5][12288];   // per half: A[128][32]@0, B[256][32]@4096 (elems)

  int tid = threadIdx.x, lane = tid & 63, w = tid >> 6;
  int wm = w >> 2, wn = w & 3;
  int fr = lane & 15, fg = lane >> 4;
  int srow = lane >> 2;                 // 0..15 (4 lanes x 16B per 64B row)
  // inverse 3-term swizzle on SOURCE col; gload_lds dest stays linear (rule 21)
  int scol = (((lane & 3) ^ (srow & 3) ^ ((srow >> 2) & 1))) * 8;

  const unsigned short* srcA = xc + (size_t)(base + m0 + 16 * w + srow) * H_DIM + scol;
  const unsigned short* srcG = wbf + (size_t)(e * I_DIM + n0 + 16 * w + srow) * H_DIM + scol;
  const unsigned short* srcU = wbf + WPE + (size_t)(e * I_DIM + n0 + 16 * w + srow) * H_DIM + scol;

  // swizzled read offsets; row&3 = fr&3, (row>>2)&1 = (fr>>2)&1 for all our rows
  int sl = ((fg ^ (fr & 3) ^ ((fr >> 2) & 1)) << 3);
  int roA[4], roB[4];
#pragma unroll
  for (int m = 0; m < 4; ++m) roA[m] = (wm * 64 + m * 16 + fr) * 32 + sl;
#pragma unroll
  for (int n = 0; n < 4; ++n) {
    int r2 = (n < 2) ? (wn * 32 + n * 16 + fr) : (128 + wn * 32 + (n - 2) * 16 + fr);
    roB[n] = 4096 + r2 * 32 + sl;
  }

  bf16x8 af[2][4], bv[2][4];
  f32x4 acc[4][4] = {};   // [m][jn]: jn 0,1 = G cols; 2,3 = U cols

#define STG1(hh)                                                     \
  do {                                                               \
    unsigned short* lb = &ls[(hh) % 5][0];                           \
    gload16(srcA + (hh) * 32, lb + w * 512);                         \
    gload16(srcG + (hh) * 32, lb + 4096 + w * 512);                  \
    gload16(srcU + (hh) * 32, lb + 4096 + (w + 8) * 512);            \
  } while (0)
#define LDF1(st, hh)                                                 \
  do {                                                               \
    const unsigned short* lb = &ls[(hh) % 5][0];                     \
    _Pragma("unroll") for (int m = 0; m < 4; ++m) af[st][m] = *(const bf16x8*)(lb + roA[m]); \
    _Pragma("unroll") for (int n = 0; n < 4; ++n) bv[st][n] = *(const bf16x8*)(lb + roB[n]); \
  } while (0)
#define MM1(st)                                                      \
  do {                                                               \
    __builtin_amdgcn_s_setprio(1);                                   \
    _Pragma("unroll") for (int m = 0; m < 4; ++m)                    \
      _Pragma("unroll") for (int n = 0; n < 4; ++n)                  \
        acc[m][n] = __builtin_amdgcn_mfma_f32_16x16x32_bf16(af[st][m], bv[st][n], acc[m][n], 0, 0, 0); \
    __builtin_amdgcn_s_setprio(0);                                   \
  } while (0)

  STG1(0); STG1(1); STG1(2); STG1(3);
  WB(6);                       // halves 0,1 landed; 2,3 in flight
  LDF1(0, 0);
#pragma unroll
  for (int i = 0; i < 32; ++i) {
    if (i + 4 < 32) STG1(i + 4);
    if (i + 1 < 32) LDF1((i + 1) & 1, i + 1);
    MM1(i & 1);
    if (i <= 27)      WB(6);
    else if (i == 28) WB(3);
    else if (i == 29) WB(0);
  }
#undef STG1
#undef LDF1
#undef MM1

#pragma unroll
  for (int m = 0; m < 4; ++m)
#pragma unroll
    for (int j = 0; j < 4; ++j) {
      int row = wm * 64 + m * 16 + fg * 4 + j;   // C/D: col=lane&15, row=(lane>>4)*4+reg
      size_t rb2 = (size_t)(base + m0 + row) * I_DIM + n0;
#pragma unroll
      for (int jn = 0; jn < 2; ++jn) {
        float g = acc[m][jn][j];
        float u = acc[m][jn + 2][j];
        h[rb2 + wn * 32 + jn * 16 + fr] = (unsigned short)f2bf(g * u / (1.f + __expf(-g)));
      }
    }
}

// ---- kernel D: gemm2: out[t] += rw * (h_e down^T). Tile M128 x N256, K=768 (24 halves),
// same depth-5 structure. grid = 8e * 16mt * 4nt = 512.
__global__ __launch_bounds__(512, 2) void gemm2_k(
    const unsigned short* __restrict__ h, const unsigned short* __restrict__ wbf,
    const int* __restrict__ wsI, const float* __restrict__ routw,
    float* __restrict__ out) {
  int e = blockIdx.x & 7, rr = blockIdx.x >> 3;
  int mt = rr & 15, nt = rr >> 4;       // nt 0..3
  int cnt = wsI[e];
  int m0 = mt * 128;
  if (m0 >= cnt) return;
  int base = ebase(wsI, e);
  int n0 = nt * 256;
  const unsigned short* down_bf = wbf + 2 * (size_t)WPE;

  __shared__ unsigned short ls[5][12288];   // A[128][32]@0, B[256][32]@4096

  int tid = threadIdx.x, lane = tid & 63, w = tid >> 6;
  int wm = w >> 2, wn = w & 3;
  int fr = lane & 15, fg = lane >> 4;
  int srow = lane >> 2;
  int scol = (((lane & 3) ^ (srow & 3) ^ ((srow >> 2) & 1))) * 8;

  const unsigned short* srcA  = h + (size_t)(base + m0 + 16 * w + srow) * I_DIM + scol;
  const unsigned short* srcB1 = down_bf + (size_t)(e * H_DIM + n0 + 16 * w + srow) * I_DIM + scol;
  const unsigned short* srcB2 = down_bf + (size_t)(e * H_DIM + n0 + 16 * (w + 8) + srow) * I_DIM + scol;

  int sl = ((fg ^ (fr & 3) ^ ((fr >> 2) & 1)) << 3);
  int roA[4], roB[4];
#pragma unroll
  for (int m = 0; m < 4; ++m) roA[m] = (wm * 64 + m * 16 + fr) * 32 + sl;
#pragma unroll
  for (int n = 0; n < 4; ++n) roB[n] = 4096 + (wn * 64 + n * 16 + fr) * 32 + sl;

  bf16x8 af[2][4], bv[2][4];
  f32x4 acc[4][4] = {};

#define STG2(hh)                                                     \
  do {                                                               \
    unsigned short* lb = &ls[(hh) % 5][0];                           \
    gload16(srcA + (hh) * 32, lb + w * 512);                         \
    gload16(srcB1 + (hh) * 32, lb + 4096 + w * 512);                 \
    gload16(srcB2 + (hh) * 32, lb + 4096 + (w + 8) * 512);           \
  } while (0)
#define LDF2(st, hh)                                                 \
  do {                                                               \
    const unsigned short* lb = &ls[(hh) % 5][0];                     \
    _Pragma("unroll") for (int m = 0; m < 4; ++m) af[st][m] = *(const bf16x8*)(lb + roA[m]); \
    _Pragma("unroll") for (int n = 0; n < 4; ++n) bv[st][n] = *(const bf16x8*)(lb + roB[n]); \
  } while (0)
#define MM2(st)                                                      \
  do {                                                               \
    __builtin_amdgcn_s_setprio(1);                                   \
    _Pragma("unroll") for (int m = 0; m < 4; ++m)                    \
      _Pragma("unroll") for (int n = 0; n < 4; ++n)                  \
        acc[m][n] = __builtin_amdgcn_mfma_f32_16x16x32_bf16(af[st][m], bv[st][n], acc[m][n], 0, 0, 0); \
    __builtin_amdgcn_s_setprio(0);                                   \
  } while (0)

  STG2(0); STG2(1); STG2(2); STG2(3);
  WB(6);
  LDF2(0, 0);
#pragma unroll
  for (int i = 0; i < 24; ++i) {
    if (i + 4 < 24) STG2(i + 4);
    if (i + 1 < 24) LDF2((i + 1) & 1, i + 1);
    MM2(i & 1);
    if (i <= 19)      WB(6);
    else if (i == 20) WB(3);
    else if (i == 21) WB(0);
  }
#undef STG2
#undef LDF2
#undef MM2

#pragma unroll
  for (int m = 0; m < 4; ++m)
#pragma unroll
    for (int j = 0; j < 4; ++j) {
      int row = wm * 64 + m * 16 + fg * 4 + j;
      int grow = m0 + row;
      if (grow < cnt) {
        int tk = wsI[64 + e * T_TOK + grow];
        float rw = routw[(size_t)tk * NEXP + e];
        float* orow = out + (size_t)tk * H_DIM + n0 + wn * 64;
#pragma unroll
        for (int n = 0; n < 4; ++n)
          atomicAdd(orow + n * 16 + fr, acc[m][n][j] * rw);
      }
    }
}

extern "C" void kernel_launch(void* const* d_in, const int* in_sizes, int n_in,
                              void* d_out, int out_size, void* d_ws, size_t ws_size,
                              hipStream_t stream) {
  const float* x      = (const float*)d_in[0];
  const float* gate_w = (const float*)d_in[1];
  const float* up_w   = (const float*)d_in[2];
  const float* down_w = (const float*)d_in[3];
  const float* routw  = (const float*)d_in[4];
  float* out = (float*)d_out;
  int* wsI = (int*)d_ws;

  unsigned short* wbf = (unsigned short*)((char*)d_ws + 131072);
  unsigned short* xc  = (unsigned short*)((char*)d_ws + 37879808);
  unsigned short* h   = (unsigned short*)((char*)d_ws + 48365568);

  compact_k<<<8, 512, 0, stream>>>(routw, wsI);
  pre_k<<<9216, 256, 0, stream>>>(x, gate_w, up_w, down_w, wsI, xc, wbf, out);
  gemm1_k<<<768, 512, 0, stream>>>(xc, wbf, wsI, h);
  gemm2_k<<<512, 512, 0, stream>>>(h, wbf, wsI, routw, out);
}